// Round 5
// baseline (226.620 us; speedup 1.0000x reference)
//
#include <hip/hip_runtime.h>
#include <math.h>

#define B_  8
#define N_  1024
#define H_  512
#define NH_ 8
#define DK_ 64
#define M_  (B_ * N_)   // 8192

typedef __attribute__((ext_vector_type(4))) float f32x4;
typedef __attribute__((ext_vector_type(8))) short bf16x8;

__device__ __forceinline__ unsigned short f2bf(float f) {
    unsigned int u = __float_as_uint(f);
    u = (u + 0x7fffu + ((u >> 16) & 1u)) >> 16;   // RNE
    return (unsigned short)u;
}

__device__ __forceinline__ float bf2f(unsigned short s) {
    return __uint_as_float(((unsigned int)s) << 16);
}

__device__ __forceinline__ float fexp2(float x) {
#if __has_builtin(__builtin_amdgcn_exp2f)
    return __builtin_amdgcn_exp2f(x);
#else
    return exp2f(x);
#endif
}

__device__ __forceinline__ void gload16(const unsigned short* g, unsigned short* l) {
    __builtin_amdgcn_global_load_lds(
        (const __attribute__((address_space(1))) void*)g,
        (__attribute__((address_space(3))) void*)l, 16, 0, 0);
}

// ---------------------------------------------------------------------------
// Fused prep: fp32->bf16 convert of x/Wq(pre-scaled)/Wk/Wv/Wg  +  adj bitmask
// pack. Segments (blocks): x 4096 | Wq 256 | Wk 256 | Wv 256 | Wg 512 |
// pack 32768 (4 mask words per block, one per wave).
// ---------------------------------------------------------------------------
__global__ __launch_bounds__(256) void prep_k(const float* __restrict__ x,
                                              const float* __restrict__ Wq,
                                              const float* __restrict__ Wk,
                                              const float* __restrict__ Wv,
                                              const float* __restrict__ Wg,
                                              const int*   __restrict__ adj,
                                              unsigned short* __restrict__ xb,
                                              unsigned short* __restrict__ wqb,
                                              unsigned short* __restrict__ wkb,
                                              unsigned short* __restrict__ wvb,
                                              unsigned short* __restrict__ wgb,
                                              unsigned long long* __restrict__ mb)
{
    int id = blockIdx.x;
    if (id >= 5376) {   // pack segment
        int gw   = (id - 5376) * 4 + (threadIdx.x >> 6);
        int lane = threadIdx.x & 63;
        int kt = gw & 15;
        int q  = (gw >> 4) & (N_ - 1);
        int b  = gw >> 14;
        int val = adj[(size_t)(b * N_ + q) * N_ + kt * 64 + lane];
        unsigned long long m = __ballot(val != 0);
        if (lane == 0) mb[gw] = m;
        return;
    }
    const float* src; unsigned short* dst; int off; float scale = 1.0f;
    if (id < 4096)      { src = x;  dst = xb;  off = id; }
    else if (id < 4352) { src = Wq; dst = wqb; off = id - 4096; scale = 0.18033688011112042f; } // 0.125*log2(e)
    else if (id < 4608) { src = Wk; dst = wkb; off = id - 4352; }
    else if (id < 4864) { src = Wv; dst = wvb; off = id - 4608; }
    else                { src = Wg; dst = wgb; off = id - 4864; }
    size_t i = (size_t)off * 1024 + threadIdx.x * 4;
    float4 v = *(const float4*)&src[i];
    *(ushort4*)&dst[i] = make_ushort4(f2bf(v.x * scale), f2bf(v.y * scale),
                                      f2bf(v.z * scale), f2bf(v.w * scale));
}

// ---------------------------------------------------------------------------
// Fused QKV projection: qkv[m][w*512 + c] = sum_k x[m][k] * W_w[c][k]
// ---------------------------------------------------------------------------
__global__ __launch_bounds__(256, 3) void proj_k(const unsigned short* __restrict__ xb,
                                                 const unsigned short* __restrict__ Wqb,
                                                 const unsigned short* __restrict__ Wkb,
                                                 const unsigned short* __restrict__ Wvb,
                                                 unsigned short* __restrict__ qkv)
{
    __shared__ unsigned short As[8192];   // [c8:0..7][row:0..127] chunks, 16 KB
    __shared__ unsigned short Bs[8192];
    const int tid = threadIdx.x;
    const int lane = tid & 63, wv = tid >> 6;
    const int ln = lane & 15, quad = lane >> 4;
    const int wm = wv >> 1, wn = wv & 1;
    const int row0 = blockIdx.x * 128;
    const int w    = blockIdx.y >> 2;
    const int col0 = (blockIdx.y & 3) * 128;
    const unsigned short* W = (w == 0) ? Wqb : ((w == 1) ? Wkb : Wvb);
    f32x4 acc[4][4] = {};

    for (int kt = 0; kt < H_; kt += 64) {
        __syncthreads();
        #pragma unroll
        for (int i = 0; i < 4; ++i) {
            int c = tid + i * 256;          // 0..1023
            int c8 = c >> 7, row = c & 127;
            gload16(&xb[(size_t)(row0 + row) * H_ + kt + c8 * 8], &As[c * 8]);
            gload16(&W [(size_t)(col0 + row) * H_ + kt + c8 * 8], &Bs[c * 8]);
        }
        __syncthreads();
        #pragma unroll
        for (int kk = 0; kk < 2; ++kk) {
            bf16x8 af[4], bf[4];
            #pragma unroll
            for (int t = 0; t < 4; ++t) {
                af[t] = *(const bf16x8*)&As[((kk * 4 + quad) * 128 + wm * 64 + t * 16 + ln) * 8];
                bf[t] = *(const bf16x8*)&Bs[((kk * 4 + quad) * 128 + wn * 64 + t * 16 + ln) * 8];
            }
            #pragma unroll
            for (int mt = 0; mt < 4; ++mt)
                #pragma unroll
                for (int nt = 0; nt < 4; ++nt)
                    acc[mt][nt] = __builtin_amdgcn_mfma_f32_16x16x32_bf16(af[mt], bf[nt], acc[mt][nt], 0, 0, 0);
        }
    }
    #pragma unroll
    for (int mt = 0; mt < 4; ++mt)
        #pragma unroll
        for (int nt = 0; nt < 4; ++nt)
            #pragma unroll
            for (int r = 0; r < 4; ++r) {
                int m = row0 + wm * 64 + mt * 16 + quad * 4 + r;
                int c = w * H_ + col0 + wn * 64 + nt * 16 + ln;
                qkv[(size_t)m * (3 * H_) + c] = f2bf(acc[mt][nt][r]);
            }
}

// ---------------------------------------------------------------------------
// v slice of qkv -> vt[((b*NH+h)*DK + d)*N + n], ushort4 stores.
// ---------------------------------------------------------------------------
__global__ __launch_bounds__(256) void transp_k(const unsigned short* __restrict__ qkv,
                                                unsigned short* __restrict__ Vt)
{
    __shared__ unsigned short Ts[64][72];
    const int bh = blockIdx.x;
    const int n0 = blockIdx.y * 64;
    const int b = bh >> 3, h = bh & 7;
    const int tid = threadIdx.x;
    #pragma unroll
    for (int p = 0; p < 2; ++p) {
        int row = (tid >> 3) + p * 32;
        int ch  = tid & 7;
        *(uint4*)&Ts[row][ch * 8] =
            *(const uint4*)&qkv[(size_t)(b * N_ + n0 + row) * (3 * H_) + 2 * H_ + h * DK_ + ch * 8];
    }
    __syncthreads();
    #pragma unroll
    for (int p = 0; p < 4; ++p) {
        int d  = (tid >> 4) + p * 16;
        int n4 = (tid & 15) * 4;
        ushort4 u = make_ushort4(Ts[n4][d], Ts[n4 + 1][d], Ts[n4 + 2][d], Ts[n4 + 3][d]);
        *(ushort4*)&Vt[((size_t)bh * DK_ + d) * N_ + n0 + n4] = u;
    }
}

// ---------------------------------------------------------------------------
// Flash attention, S^T formulation, K-split 2: each block does 8 of 16
// key-tiles for a (b, head, 128-q tile). Double-buffered K/V staging.
// Stores UNNORMALIZED partial O^T (bf16) + partial sum-of-p (f32); the
// no-max-sub softmax makes the cross-split combine an exact sum.
// ---------------------------------------------------------------------------
__global__ __launch_bounds__(256, 3) void attn_k(const unsigned short* __restrict__ qkv,
                                                 const unsigned short* __restrict__ Vt,
                                                 const unsigned long long* __restrict__ Mb,
                                                 unsigned short* __restrict__ po,
                                                 float* __restrict__ pl)
{
    const int qt   = blockIdx.x & 7;
    const int head = (blockIdx.x >> 3) & 7;
    const int b    = (blockIdx.x >> 6) & 7;
    const int s    = blockIdx.x >> 9;            // split 0/1
    const int t0   = s * 8;

    __shared__ unsigned short Ks[2][4096];       // [c8:0..7][row:0..63] chunks
    __shared__ unsigned short Vs[2][4096];
    __shared__ unsigned short Ps[4][2][16][72];  // per-wave, per-group: [q=ln][key]

    const int tid = threadIdx.x;
    const int lane = tid & 63, wv = tid >> 6;
    const int ln = lane & 15, quad = lane >> 4;
    const int q0 = qt * 128 + wv * 32 + ln;
    const int q1 = q0 + 16;

    const unsigned short* Kbase = qkv + H_ + head * DK_;
    const unsigned short* Vbase = Vt + (size_t)(b * NH_ + head) * DK_ * N_;

    bf16x8 bq[2][2];
    #pragma unroll
    for (int kk = 0; kk < 2; ++kk) {
        bq[0][kk] = *(const bf16x8*)&qkv[(size_t)(b * N_ + q0) * (3 * H_) + head * DK_ + kk * 32 + quad * 8];
        bq[1][kk] = *(const bf16x8*)&qkv[(size_t)(b * N_ + q1) * (3 * H_) + head * DK_ + kk * 32 + quad * 8];
    }

    f32x4 o[2][4] = {};
    float psum[2] = {0.f, 0.f};

    auto issue = [&](int t, int bi) {
        #pragma unroll
        for (int i = 0; i < 2; ++i) {
            int c = tid + i * 256;               // 0..511
            int c8 = c >> 6, row = c & 63;
            gload16(&Kbase[(size_t)(b * N_ + t * 64 + row) * (3 * H_) + c8 * 8], &Ks[bi][c * 8]);
            gload16(&Vbase[(size_t)row * N_ + t * 64 + c8 * 8], &Vs[bi][c * 8]);
        }
    };

    issue(t0, 0);

    for (int t = t0; t < t0 + 8; ++t) {
        __syncthreads();                         // tile t visible
        if (t < t0 + 7) issue(t + 1, (t + 1) & 1);
        const unsigned short* Kc = Ks[t & 1];
        const unsigned short* Vc = Vs[t & 1];

        unsigned long long mq[2];
        mq[0] = Mb[(size_t)(b * N_ + q0) * 16 + t];
        mq[1] = Mb[(size_t)(b * N_ + q1) * 16 + t];

        f32x4 sv[2][4] = {};
        #pragma unroll
        for (int kk = 0; kk < 2; ++kk)
            #pragma unroll
            for (int nt = 0; nt < 4; ++nt) {
                bf16x8 ka = *(const bf16x8*)&Kc[((kk * 4 + quad) * 64 + nt * 16 + ln) * 8];
                sv[0][nt] = __builtin_amdgcn_mfma_f32_16x16x32_bf16(ka, bq[0][kk], sv[0][nt], 0, 0, 0);
                sv[1][nt] = __builtin_amdgcn_mfma_f32_16x16x32_bf16(ka, bq[1][kk], sv[1][nt], 0, 0, 0);
            }

        #pragma unroll
        for (int g = 0; g < 2; ++g) {
            unsigned long long sh = mq[g] >> (quad * 4);
            #pragma unroll
            for (int nt = 0; nt < 4; ++nt) {
                unsigned int bn = (unsigned int)(sh >> (nt * 16)) & 0xFu;
                float p[4];
                #pragma unroll
                for (int r = 0; r < 4; ++r) {
                    float e = fexp2(sv[g][nt][r]);
                    p[r] = (bn & (1u << r)) ? e : 0.f;
                    psum[g] += p[r];
                }
                unsigned int d0 = __builtin_amdgcn_perm(__float_as_uint(p[1]), __float_as_uint(p[0]), 0x07060302u);
                unsigned int d1 = __builtin_amdgcn_perm(__float_as_uint(p[3]), __float_as_uint(p[2]), 0x07060302u);
                *(uint2*)&Ps[wv][g][ln][nt * 16 + quad * 4] = make_uint2(d0, d1);
            }
        }

        bf16x8 pb[2][2];
        #pragma unroll
        for (int g = 0; g < 2; ++g)
            #pragma unroll
            for (int kk = 0; kk < 2; ++kk)
                pb[g][kk] = *(const bf16x8*)&Ps[wv][g][ln][kk * 32 + quad * 8];

        #pragma unroll
        for (int kk = 0; kk < 2; ++kk)
            #pragma unroll
            for (int dt = 0; dt < 4; ++dt) {
                bf16x8 va = *(const bf16x8*)&Vc[((kk * 4 + quad) * 64 + dt * 16 + ln) * 8];
                o[0][dt] = __builtin_amdgcn_mfma_f32_16x16x32_bf16(va, pb[0][kk], o[0][dt], 0, 0, 0);
                o[1][dt] = __builtin_amdgcn_mfma_f32_16x16x32_bf16(va, pb[1][kk], o[1][dt], 0, 0, 0);
            }
    }

    unsigned short* pos = po + (size_t)s * M_ * H_;
    float* pls = pl + (size_t)s * M_ * NH_;
    #pragma unroll
    for (int g = 0; g < 2; ++g) {
        psum[g] += __shfl_xor(psum[g], 16);
        psum[g] += __shfl_xor(psum[g], 32);
        int qg = (g == 0) ? q0 : q1;
        if (quad == 0) pls[(size_t)(b * N_ + qg) * NH_ + head] = psum[g];
        #pragma unroll
        for (int dt = 0; dt < 4; ++dt) {
            ushort4 u = make_ushort4(f2bf(o[g][dt][0]), f2bf(o[g][dt][1]),
                                     f2bf(o[g][dt][2]), f2bf(o[g][dt][3]));
            *(ushort4*)&po[(size_t)s * M_ * H_ + (size_t)(b * N_ + qg) * H_ + head * DK_ + dt * 16 + quad * 4] = u;
        }
    }
    (void)pos;
}

// ---------------------------------------------------------------------------
// Combine K-splits: cmb = (po0 + po1) / (pl0 + pl1), bf16 out.
// ---------------------------------------------------------------------------
__global__ __launch_bounds__(256) void comb_k(const unsigned short* __restrict__ po,
                                              const float* __restrict__ pl,
                                              unsigned short* __restrict__ cmb)
{
    size_t i = ((size_t)blockIdx.x * 256 + threadIdx.x) * 4;
    int m = (int)(i >> 9);
    int f = (int)(i & 511);
    int head = f >> 6;
    ushort4 a = *(const ushort4*)&po[i];
    ushort4 c = *(const ushort4*)&po[(size_t)M_ * H_ + i];
    float l = pl[(size_t)m * NH_ + head] + pl[(size_t)M_ * NH_ + (size_t)m * NH_ + head];
    float inv = 1.f / l;
    ushort4 u = make_ushort4(f2bf((bf2f(a.x) + bf2f(c.x)) * inv),
                             f2bf((bf2f(a.y) + bf2f(c.y)) * inv),
                             f2bf((bf2f(a.z) + bf2f(c.z)) * inv),
                             f2bf((bf2f(a.w) + bf2f(c.w)) * inv));
    *(ushort4*)&cmb[i] = u;
}

// ---------------------------------------------------------------------------
// Gate GEMM (K=1024, A=[cmb|xb] bf16) + sigmoid + residual, fp32 out.
// ---------------------------------------------------------------------------
__global__ __launch_bounds__(256, 2) void gate_k(const unsigned short* __restrict__ cmb,
                                                 const unsigned short* __restrict__ xb,
                                                 const unsigned short* __restrict__ Wgb,
                                                 const float* __restrict__ bgp,
                                                 const float* __restrict__ X,
                                                 float* __restrict__ out)
{
    __shared__ unsigned short As[8192];   // [c8][row 0..127], 16 KB
    __shared__ unsigned short Bs[4096];   // [c8][row 0..63],   8 KB
    const int tid = threadIdx.x;
    const int lane = tid & 63, wv = tid >> 6;
    const int ln = lane & 15, quad = lane >> 4;
    const int wm = wv >> 1, wn = wv & 1;
    const int row0 = blockIdx.x * 128;
    const int col0 = blockIdx.y * 64;
    f32x4 acc[4][2] = {};

    for (int kt = 0; kt < 2 * H_; kt += 64) {
        const unsigned short* Asrc = (kt < H_) ? cmb : xb;
        const int ko = kt & (H_ - 1);
        __syncthreads();
        #pragma unroll
        for (int i = 0; i < 4; ++i) {
            int c = tid + i * 256;
            int c8 = c >> 7, row = c & 127;
            gload16(&Asrc[(size_t)(row0 + row) * H_ + ko + c8 * 8], &As[c * 8]);
        }
        #pragma unroll
        for (int i = 0; i < 2; ++i) {
            int c = tid + i * 256;
            int c8 = c >> 6, row = c & 63;
            gload16(&Wgb[(size_t)(col0 + row) * (2 * H_) + kt + c8 * 8], &Bs[c * 8]);
        }
        __syncthreads();
        #pragma unroll
        for (int kk = 0; kk < 2; ++kk) {
            bf16x8 af[4], bf[2];
            #pragma unroll
            for (int t = 0; t < 4; ++t)
                af[t] = *(const bf16x8*)&As[((kk * 4 + quad) * 128 + wm * 64 + t * 16 + ln) * 8];
            #pragma unroll
            for (int t = 0; t < 2; ++t)
                bf[t] = *(const bf16x8*)&Bs[((kk * 4 + quad) * 64 + wn * 32 + t * 16 + ln) * 8];
            #pragma unroll
            for (int mt = 0; mt < 4; ++mt)
                #pragma unroll
                for (int nt = 0; nt < 2; ++nt)
                    acc[mt][nt] = __builtin_amdgcn_mfma_f32_16x16x32_bf16(af[mt], bf[nt], acc[mt][nt], 0, 0, 0);
        }
    }
    #pragma unroll
    for (int mt = 0; mt < 4; ++mt)
        #pragma unroll
        for (int nt = 0; nt < 2; ++nt)
            #pragma unroll
            for (int r = 0; r < 4; ++r) {
                int m = row0 + wm * 64 + mt * 16 + quad * 4 + r;
                int c = col0 + wn * 32 + nt * 16 + ln;
                float g  = 1.f / (1.f + __expf(-(acc[mt][nt][r] + bgp[c])));
                float xv = X[(size_t)m * H_ + c];
                float cv = bf2f(cmb[(size_t)m * H_ + c]);
                out[(size_t)m * H_ + c] = g * xv + (1.f - g) * cv;
            }
}

// ---------------------------------------------------------------------------
extern "C" void kernel_launch(void* const* d_in, const int* in_sizes, int n_in,
                              void* d_out, int out_size, void* d_ws, size_t ws_size,
                              hipStream_t stream)
{
    const float* x   = (const float*)d_in[0];
    const int*   adj = (const int*)  d_in[1];
    const float* Wq  = (const float*)d_in[2];
    const float* Wk  = (const float*)d_in[3];
    const float* Wv  = (const float*)d_in[4];
    const float* Wg  = (const float*)d_in[5];
    const float* bg  = (const float*)d_in[6];
    float* out = (float*)d_out;

    unsigned short* xb  = (unsigned short*)d_ws;                      // 8 MB
    unsigned short* wqb = xb  + (size_t)M_ * H_;                      // 512 KB
    unsigned short* wkb = wqb + (size_t)H_ * H_;
    unsigned short* wvb = wkb + (size_t)H_ * H_;
    unsigned short* wgb = wvb + (size_t)H_ * H_;                      // 1 MB
    unsigned short* qkv = wgb + (size_t)H_ * 2 * H_;                  // 24 MB
    unsigned short* vt  = qkv + (size_t)M_ * 3 * H_;                  // 8 MB
    unsigned short* cmb = vt  + (size_t)M_ * H_;                      // 8 MB
    unsigned short* po  = cmb + (size_t)M_ * H_;                      // 16 MB (2 splits)
    float*          pl  = (float*)(po + (size_t)2 * M_ * H_);         // 512 KB
    unsigned long long* mb = (unsigned long long*)(pl + (size_t)2 * M_ * NH_);  // 1 MB

    prep_k<<<5376 + 32768, 256, 0, stream>>>(x, Wq, Wk, Wv, Wg, adj,
                                             xb, wqb, wkb, wvb, wgb, mb);

    proj_k<<<dim3(M_ / 128, 12), 256, 0, stream>>>(xb, wqb, wkb, wvb, qkv);

    transp_k<<<dim3(B_ * NH_, N_ / 64), 256, 0, stream>>>(qkv, vt);

    attn_k<<<B_ * NH_ * (N_ / 128) * 2, 256, 0, stream>>>(qkv, vt, mb, po, pl);

    comb_k<<<M_ * H_ / 1024, 256, 0, stream>>>(po, pl, cmb);

    gate_k<<<dim3(M_ / 128, H_ / 64), 256, 0, stream>>>(cmb, xb, wgb, bg, x, out);
}